// Round 6
// baseline (738.401 us; speedup 1.0000x reference)
//
#include <hip/hip_runtime.h>
#include <hip/hip_bf16.h>
#include <stdint.h>

#define HIDDEN 1024
#define OUTD   512
#define NSEQ   8192
#define MTOT   16384  // 2*NSEQ

typedef unsigned short u16;
typedef __attribute__((ext_vector_type(8))) short short8;  // 8 bf16 (4 VGPRs)
typedef __attribute__((ext_vector_type(4))) float f32x4;

__device__ __forceinline__ u16 f2b(float f){
  union { __hip_bfloat16 h; u16 u; } c; c.h = __float2bfloat16(f); return c.u;
}

__device__ __forceinline__ void gload_lds16(const void* g, void* l){
  __builtin_amdgcn_global_load_lds(
    (const __attribute__((address_space(1))) uint32_t*)(uintptr_t)g,
    (__attribute__((address_space(3))) uint32_t*)(uintptr_t)l, 16, 0, 0);
}

#define MFMA16(a,b,c) __builtin_amdgcn_mfma_f32_16x16x32_bf16((a),(b),(c),0,0,0)

// ---------------- f32 -> bf16 convert ----------------
__global__ void cvt_bf16_kernel(const float* __restrict__ in, u16* __restrict__ out, int n4){
  int i = blockIdx.x*blockDim.x + threadIdx.x;
  int stride = gridDim.x*blockDim.x;
  for (; i < n4; i += stride){
    float4 v = ((const float4*)in)[i];
    ushort4 o;
    o.x = f2b(v.x); o.y = f2b(v.y); o.z = f2b(v.z); o.w = f2b(v.w);
    ((ushort4*)out)[i] = o;
  }
}

// ---------------- transpose f32[R][C] -> bf16[C][R] ----------------
__global__ void transpose_bf16_kernel(const float* __restrict__ in, u16* __restrict__ out, int R, int C){
  __shared__ float t[32][33];
  int tx = threadIdx.x, ty = threadIdx.y;
  int c0 = blockIdx.x*32, r0 = blockIdx.y*32;
  #pragma unroll
  for (int i = ty; i < 32; i += 8) t[i][tx] = in[(size_t)(r0+i)*C + c0 + tx];
  __syncthreads();
  #pragma unroll
  for (int i = ty; i < 32; i += 8) out[(size_t)(c0+i)*R + r0 + tx] = f2b(t[tx][i]);
}

// ---------------- GEMM: C[M,N] = A[M,K] @ BT[N,K]^T (+bias, opt ELU, *scale), bf16 out ----
template<bool ELU_ACT, bool BIAS_ROW>
__global__ __launch_bounds__(256, 2) void gemm_bt(
    const u16* __restrict__ A, const u16* __restrict__ BT,
    const float* __restrict__ bias, u16* __restrict__ C,
    int M, int N, int K, float outscale)
{
  __shared__ u16 As[128*32];
  __shared__ u16 Bs[128*32];
  const int tid = threadIdx.x;
  const int w = tid >> 6, l = tid & 63;
  const int lr = l & 15, lg = l >> 4;
  const int brow = blockIdx.y * 128, bcol = blockIdx.x * 128;
  const int wr = w >> 1, wc = w & 1;
  f32x4 acc[4][4];
  #pragma unroll
  for (int i=0;i<4;i++)
    #pragma unroll
    for (int j=0;j<4;j++) acc[i][j] = f32x4{0.f,0.f,0.f,0.f};

  for (int k0 = 0; k0 < K; k0 += 32){
    __syncthreads();
    {
      int sb = w*64;
      int s0 = sb + l;
      int s1 = 256 + sb + l;
      gload_lds16(A  + (size_t)(brow + (s0>>2))*K + k0 + (s0&3)*8, As + sb*8);
      gload_lds16(A  + (size_t)(brow + (s1>>2))*K + k0 + (s1&3)*8, As + (256+sb)*8);
      gload_lds16(BT + (size_t)(bcol + (s0>>2))*K + k0 + (s0&3)*8, Bs + sb*8);
      gload_lds16(BT + (size_t)(bcol + (s1>>2))*K + k0 + (s1&3)*8, Bs + (256+sb)*8);
    }
    __syncthreads();
    short8 a[4], b[4];
    #pragma unroll
    for (int i=0;i<4;i++){
      a[i] = *(const short8*)(As + (wr*64 + i*16 + lr)*32 + lg*8);
      b[i] = *(const short8*)(Bs + (wc*64 + i*16 + lr)*32 + lg*8);
    }
    #pragma unroll
    for (int i=0;i<4;i++)
      #pragma unroll
      for (int j=0;j<4;j++)
        acc[i][j] = MFMA16(a[i], b[j], acc[i][j]);
  }

  // C/D layout (m89-verified): col = lane&15, row = (lane>>4)*4 + reg
  #pragma unroll
  for (int i=0;i<4;i++)
    #pragma unroll
    for (int j=0;j<4;j++){
      int col = bcol + wc*64 + j*16 + lr;
      float bc = BIAS_ROW ? 0.f : bias[col];
      #pragma unroll
      for (int r=0;r<4;r++){
        int row = brow + wr*64 + i*16 + lg*4 + r;
        float v = acc[i][j][r] + (BIAS_ROW ? bias[row] : bc);
        if (ELU_ACT) v = v > 0.f ? v : expm1f(v);
        v *= outscale;
        C[(size_t)row*N + col] = f2b(v);
      }
    }
}

// ---------------- flash attention v4: d-sliced PV ----------------
// 512 threads (8 waves), 16 q-rows/wave for QK+softmax -> 128 q-rows/block.
// KV-split x2: grid = 256 = {dir x half x 64 q-blocks}; partials + merge.
// QK: S = mfma(K_A, Q_B), lane holds P-row for q=lane&15 (per-lane softmax).
// P[128 q][32 kv] shared in LDS; corr[128] broadcast for deferred rescale.
// PV d-sliced: wave w computes O[d in w*64..w*64+64)][all 128 q] reading only
// its 64 Vt rows (V LDS traffic 8x lower than v3) + all waves' P.
__global__ __launch_bounds__(512, 2) void flash_attn(
    const u16* __restrict__ Qb, const u16* __restrict__ Kb,
    const u16* __restrict__ Vt, float* __restrict__ Opart,
    float2* __restrict__ MLpart)
{
  __shared__ u16 Ks[2][32*512];    // K tile  [kv=32][d=512], 16B-slot XOR-swizzle (row&7)
  __shared__ u16 Vts[2][512*32];   // Vt tile [d=512][kv=32], slot swizzle (d^(d>>2))&3
  __shared__ u16 Plds[128*32];     // P [q=128][kv=32], 16B-slot swizzle T^(q&3)
  __shared__ float corr_s[128];
  __shared__ float flag_s[8];
  const int tid = threadIdx.x;
  const int w = tid >> 6, l = tid & 63;
  const int lr = l & 15, lg = l >> 4;
  // XCD-aware: xcd = bx&7; (dir,half) per XCD-pair; 64 CUs share one KV stream
  const int xcd = blockIdx.x & 7;
  const int idx = blockIdx.x >> 3;          // 0..31
  const int dir = xcd >> 2;                 // 0..1
  const int half = (xcd >> 1) & 1;          // 0..1
  const int qb  = (xcd & 1)*32 + idx;       // 0..63
  const int qrow0 = dir*NSEQ + qb*128 + w*16;
  const int kv0 = (1-dir)*NSEQ + half*(NSEQ/2);
  const int NT = (NSEQ/2)/32;               // 128 tiles

  // Q fragments (B-operand): col=q=lr, k = kt*32 + lg*8
  short8 qf[16];
  #pragma unroll
  for (int kt=0; kt<16; kt++)
    qf[kt] = *(const short8*)(Qb + (size_t)(qrow0 + lr)*OUTD + kt*32 + lg*8);

  // O[d][q]: d = w*64 + dt*16 + lg*4 + r, q = qt*16 + lr
  f32x4 o[4][8];
  #pragma unroll
  for (int dt=0;dt<4;dt++)
    #pragma unroll
    for (int qt=0;qt<8;qt++) o[dt][qt] = f32x4{0.f,0.f,0.f,0.f};
  float m = -1e30f, ls = 0.f;               // per-lane scalars (q = w*16+lr)

  // incremental staging pointers (address math hoisted out of the loop)
  const u16* kp[4];
  const u16* vp[4];
  #pragma unroll
  for (int i=0;i<4;i++){
    int g = w*4 + i;                        // kv row 0..31
    kp[i] = Kb + (size_t)(kv0 + g)*OUTD + ((l ^ (g&7))*8);
    int d = g*16 + (l>>2);                  // Vt row 0..511
    int fd = (d ^ (d>>2)) & 3;
    vp[i] = Vt + (size_t)d*MTOT + kv0 + (((l&3) ^ fd)*8);
  }

  auto STAGE = [&](int buf){
    u16* Kd = &Ks[buf][0];
    u16* Vd = &Vts[buf][0];
    #pragma unroll
    for (int i=0;i<4;i++) gload_lds16(kp[i], Kd + (w*4+i)*512);
    #pragma unroll
    for (int i=0;i<4;i++) gload_lds16(vp[i], Vd + ((w*4+i)*64 + l)*8);
    #pragma unroll
    for (int i=0;i<4;i++){ kp[i] += 32*OUTD; vp[i] += 32; }
  };

  STAGE(0);
  __syncthreads();

  for (int t=0; t<NT; t++){
    const int cur = t & 1;
    if (t+1 < NT) STAGE(cur^1);            // overlap with compute below

    const u16* Kc = &Ks[cur][0];
    const u16* Vc = &Vts[cur][0];

    // S = mfma(K_A, Q_B): s0 rows kv 0..15, s1 rows kv 16..31; col = q = lr
    f32x4 s0 = f32x4{0.f,0.f,0.f,0.f}, s1 = s0;
    __builtin_amdgcn_s_setprio(1);
    #pragma unroll
    for (int kt=0; kt<16; kt++){
      short8 ka = *(const short8*)(Kc + (size_t)(lr)*512    + (((kt*4+lg) ^ (lr&7))*8));
      short8 kb = *(const short8*)(Kc + (size_t)(16+lr)*512 + (((kt*4+lg) ^ (lr&7))*8));
      s0 = MFMA16(ka, qf[kt], s0);
      s1 = MFMA16(kb, qf[kt], s1);
    }
    __builtin_amdgcn_s_setprio(0);

    // per-lane online softmax for q=w*16+lr over kv = lg*4+r (s0), 16+lg*4+r (s1)
    float mx = fmaxf(fmaxf(fmaxf(s0[0],s0[1]), fmaxf(s0[2],s0[3])),
                     fmaxf(fmaxf(s1[0],s1[1]), fmaxf(s1[2],s1[3])));
    mx = fmaxf(mx, __shfl_xor(mx, 16));
    mx = fmaxf(mx, __shfl_xor(mx, 32));
    float corr = 1.f;
    bool needany = __any(mx > m + 8.f);     // defer-max THR=8 (wave-uniform)
    if (needany){
      float mn = fmaxf(m, mx);
      corr = exp2f((m - mn)*1.44269504f);
      m = mn; ls *= corr;
    }
    if (lg == 0) corr_s[w*16 + lr] = corr;
    if (l == 0)  flag_s[w] = needany ? 1.f : 0.f;

    float p0[4], p1[4], sm = 0.f;
    #pragma unroll
    for (int r=0;r<4;r++){
      p0[r] = exp2f((s0[r]-m)*1.44269504f);
      p1[r] = exp2f((s1[r]-m)*1.44269504f);
      sm += p0[r] + p1[r];
    }
    sm += __shfl_xor(sm, 16);
    sm += __shfl_xor(sm, 32);
    ls += sm;

    // P -> LDS: row q = w*16+lr; kv 4lg..4lg+3 (p0) and 16+4lg.. (p1).
    // 16B-slot swizzle T' = T ^ (q&3); 8B half = lg&1 kept in place.
    {
      int q = w*16 + lr;
      ushort4 w0, w1;
      w0.x = f2b(p0[0]); w0.y = f2b(p0[1]); w0.z = f2b(p0[2]); w0.w = f2b(p0[3]);
      w1.x = f2b(p1[0]); w1.y = f2b(p1[1]); w1.z = f2b(p1[2]); w1.w = f2b(p1[3]);
      int T0 = ((lg>>1)     ^ (q&3));
      int T1 = ((2+(lg>>1)) ^ (q&3));
      *(ushort4*)(Plds + q*32 + T0*8 + (lg&1)*4) = w0;
      *(ushort4*)(Plds + q*32 + T1*8 + (lg&1)*4) = w1;
    }
    __syncthreads();   // B1: P + corr + flags visible to all waves

    // deferred rescale of O columns (block-uniform branch, rare)
    float fsum = flag_s[0]+flag_s[1]+flag_s[2]+flag_s[3]
               + flag_s[4]+flag_s[5]+flag_s[6]+flag_s[7];
    if (fsum > 0.f){
      float cc[8];
      #pragma unroll
      for (int qt=0;qt<8;qt++) cc[qt] = corr_s[qt*16 + lr];
      #pragma unroll
      for (int dt=0;dt<4;dt++)
        #pragma unroll
        for (int qt=0;qt<8;qt++){
          o[dt][qt][0] *= cc[qt]; o[dt][qt][1] *= cc[qt];
          o[dt][qt][2] *= cc[qt]; o[dt][qt][3] *= cc[qt];
        }
    }

    // PV d-sliced: wave w owns d in [w*64, w*64+64)
    __builtin_amdgcn_s_setprio(1);
    short8 va[4];
    #pragma unroll
    for (int dt=0;dt<4;dt++){
      int d = w*64 + dt*16 + lr;
      int fd = (d ^ (d>>2)) & 3;
      va[dt] = *(const short8*)(Vc + d*32 + ((lg ^ fd)*8));
    }
    #pragma unroll
    for (int qt=0; qt<8; qt++){
      short8 pb = *(const short8*)(Plds + (qt*16+lr)*32 + ((lg ^ (lr&3))*8));
      #pragma unroll
      for (int dt=0;dt<4;dt++)
        o[dt][qt] = MFMA16(va[dt], pb, o[dt][qt]);
    }
    __builtin_amdgcn_s_setprio(0);

    __syncthreads();   // B2: PV done (P reusable), staging drained
  }

  // write unnormalized partials: O~ (d-slice per wave, all 128 q), (m, ls) per owner q
  #pragma unroll
  for (int qt=0; qt<8; qt++){
    size_t qg = (size_t)(dir*NSEQ + qb*128 + qt*16 + lr);
    float* row = Opart + ((size_t)half*MTOT + qg)*OUTD + w*64;
    #pragma unroll
    for (int dt=0; dt<4; dt++)
      *(f32x4*)(row + dt*16 + lg*4) = o[dt][qt];
  }
  if (lg == 0){
    int qg = dir*NSEQ + qb*128 + w*16 + lr;
    MLpart[half*MTOT + qg] = make_float2(m, ls);
  }
}

// ---------------- merge the two KV-half partials ----------------
__global__ void merge_kernel(const float* __restrict__ Opart,
                             const float2* __restrict__ MLpart,
                             float* __restrict__ out){
  int i = blockIdx.x*blockDim.x + threadIdx.x;   // over MTOT*128 float4s
  int qg = i >> 7, d4 = i & 127;
  float2 ml0 = MLpart[qg], ml1 = MLpart[MTOT + qg];
  float M = fmaxf(ml0.x, ml1.x);
  float w0 = exp2f((ml0.x - M)*1.44269504f);
  float w1 = exp2f((ml1.x - M)*1.44269504f);
  float inv = 1.f / (ml0.y*w0 + ml1.y*w1);
  f32x4 a = ((const f32x4*)Opart)[(size_t)qg*128 + d4];
  f32x4 b = ((const f32x4*)Opart)[(size_t)MTOT*128 + (size_t)qg*128 + d4];
  f32x4 r;
  #pragma unroll
  for (int j=0;j<4;j++) r[j] = (a[j]*w0 + b[j]*w1)*inv;
  int row = qg & (NSEQ-1), dir = qg >> 13;
  ((f32x4*)out)[(size_t)row*256 + dir*128 + d4] = r;
}

// ---------------- workspace layout ----------------
#define OFF_W1T  ((size_t)0)                          // 1024*1024*2
#define OFF_W2T  (OFF_W1T + (size_t)1024*1024*2)      // 512*1024*2
#define OFF_WQT  (OFF_W2T + (size_t)512*1024*2)       // 512*512*2
#define OFF_WKT  (OFF_WQT + (size_t)512*512*2)
#define OFF_WVT  (OFF_WKT + (size_t)512*512*2)
#define OFF_XC   (OFF_WVT + (size_t)512*512*2)        // 16384*1024*2 (later: Qb,Kb)
#define OFF_H    (OFF_XC  + (size_t)MTOT*HIDDEN*2)    // 16384*1024*2 (later: Vt)
#define OFF_P    (OFF_H   + (size_t)MTOT*HIDDEN*2)    // 16384*512*2
#define OFF_QB   OFF_XC
#define OFF_KB   (OFF_XC + (size_t)MTOT*OUTD*2)
#define OFF_VT   OFF_H
#define OFF_ML   (OFF_P  + (size_t)MTOT*OUTD*2)       // 2*16384*float2
#define OFF_OP   (OFF_ML + (size_t)2*MTOT*8)          // 2*16384*512*f32 = 64MB

extern "C" void kernel_launch(void* const* d_in, const int* in_sizes, int n_in,
                              void* d_out, int out_size, void* d_ws, size_t ws_size,
                              hipStream_t stream) {
  const float* za = (const float*)d_in[0];
  const float* zb = (const float*)d_in[1];
  const float* W1 = (const float*)d_in[2];
  const float* b1 = (const float*)d_in[3];
  const float* W2 = (const float*)d_in[4];
  const float* b2 = (const float*)d_in[5];
  const float* Wq = (const float*)d_in[6];
  const float* bq = (const float*)d_in[7];
  const float* Wk = (const float*)d_in[8];
  const float* bk = (const float*)d_in[9];
  const float* Wv = (const float*)d_in[10];
  const float* bv = (const float*)d_in[11];
  float* out = (float*)d_out;
  char* ws = (char*)d_ws;

  u16* W1T = (u16*)(ws + OFF_W1T);
  u16* W2T = (u16*)(ws + OFF_W2T);
  u16* WqT = (u16*)(ws + OFF_WQT);
  u16* WkT = (u16*)(ws + OFF_WKT);
  u16* WvT = (u16*)(ws + OFF_WVT);
  u16* Xc  = (u16*)(ws + OFF_XC);
  u16* H   = (u16*)(ws + OFF_H);
  u16* P   = (u16*)(ws + OFF_P);
  u16* Qb  = (u16*)(ws + OFF_QB);
  u16* Kb  = (u16*)(ws + OFF_KB);
  u16* Vt  = (u16*)(ws + OFF_VT);
  float2* ML = (float2*)(ws + OFF_ML);
  float*  OP = (float*)(ws + OFF_OP);

  // inputs -> bf16 (za | zb stacked)
  cvt_bf16_kernel<<<2048, 256, 0, stream>>>(za, Xc, NSEQ*HIDDEN/4);
  cvt_bf16_kernel<<<2048, 256, 0, stream>>>(zb, Xc + (size_t)NSEQ*HIDDEN, NSEQ*HIDDEN/4);
  // weight transposes (f32 -> bf16)
  transpose_bf16_kernel<<<dim3(32,32), dim3(32,8), 0, stream>>>(W1, W1T, 1024, 1024);
  transpose_bf16_kernel<<<dim3(16,32), dim3(32,8), 0, stream>>>(W2, W2T, 1024, 512);
  transpose_bf16_kernel<<<dim3(16,16), dim3(32,8), 0, stream>>>(Wq, WqT, 512, 512);
  transpose_bf16_kernel<<<dim3(16,16), dim3(32,8), 0, stream>>>(Wk, WkT, 512, 512);
  transpose_bf16_kernel<<<dim3(16,16), dim3(32,8), 0, stream>>>(Wv, WvT, 512, 512);

  // H = ELU(Xc @ W1 + b1)    [16384,1024]
  gemm_bt<true,false><<<dim3(HIDDEN/128, MTOT/128), 256, 0, stream>>>(
      Xc, W1T, b1, H, MTOT, HIDDEN, HIDDEN, 1.f);
  // P = H @ W2 + b2          [16384,512]
  gemm_bt<false,false><<<dim3(OUTD/128, MTOT/128), 256, 0, stream>>>(
      H, W2T, b2, P, MTOT, OUTD, HIDDEN, 1.f);
  // Qb = (P @ Wq + bq)/16    [16384,512]   (scale folded in)
  gemm_bt<false,false><<<dim3(OUTD/128, MTOT/128), 256, 0, stream>>>(
      P, WqT, bq, Qb, MTOT, OUTD, OUTD, 0.0625f);
  // Kb = P @ Wk + bk         [16384,512]
  gemm_bt<false,false><<<dim3(OUTD/128, MTOT/128), 256, 0, stream>>>(
      P, WkT, bk, Kb, MTOT, OUTD, OUTD, 1.f);
  // Vt = (P @ Wv + bv)^T as GEMM: Vt[d,j] = sum_k WvT[d,k]*P[j,k] + bv[d]   [512,16384]
  gemm_bt<false,true><<<dim3(MTOT/128, OUTD/128), 256, 0, stream>>>(
      WvT, P, bv, Vt, OUTD, MTOT, OUTD, 1.f);

  // flash attention (partials), then merge
  flash_attn<<<256, 512, 0, stream>>>(Qb, Kb, Vt, OP, ML);
  merge_kernel<<<(MTOT*128)/256, 256, 0, stream>>>(OP, ML, out);
}